// Round 10
// baseline (1073.480 us; speedup 1.0000x reference)
//
#include <hip/hip_runtime.h>
#include <hip/hip_fp16.h>

// Graph_NN: 3-layer SAGE (gcn aggregator), N=100000, E=1600000, D=128, fp32.
// R10: (a) binned CSR fill: k_bin appends (src,dst) to per-bucket regions
//      (bucket=dst>>8; starts come free from row_ptr) -> write lines stay
//      L2-hot (~12.8MB traffic vs 102MB of random line allocs); k_fill2
//      scatters within one bucket/block using LDS cursors (writes land in a
//      ~16KB hot window). Replaces k_fill (87us, 1.2 TB/s random-write path).
// (b) eal packed to 32 bits: src(17b) | ann(13b)<<17 -> half the edge-list
//     bytes everywhere.
// (c) embW stored fp16; all 3 layer-aggs unified into one templated 256B-row
//     kernel (L1 table = 1.28MB, per-XCD-L2-resident).
// Aggs at ~4 TB/s random-row ceiling (measured R9); bytes are the only lever.

#define D 128
#define SRC_MASK 0x1FFFF   // 17 bits for src (N=100000 < 2^17)

// ---------- CSR build ----------
__global__ void k_count(const int* __restrict__ dst, int* __restrict__ deg, int E) {
    int e = blockIdx.x * blockDim.x + threadIdx.x;
    if (e < E) atomicAdd(&deg[dst[e]], 1);
}

__global__ void k_bsum(const int* __restrict__ deg, int* __restrict__ bsum, int n) {
    __shared__ int s[256];
    int t = threadIdx.x, i = blockIdx.x * 256 + t;
    s[t] = (i < n) ? deg[i] : 0;
    __syncthreads();
    for (int off = 128; off > 0; off >>= 1) { if (t < off) s[t] += s[t + off]; __syncthreads(); }
    if (t == 0) bsum[blockIdx.x] = s[0];
}

__global__ void k_scanb(int* __restrict__ bsum, int nb, int* __restrict__ row_ptr, int N, int E) {
    __shared__ int s[512];
    int t = threadIdx.x;
    int v = (t < nb) ? bsum[t] : 0;
    s[t] = v;
    __syncthreads();
    for (int off = 1; off < 512; off <<= 1) {
        int x = (t >= off) ? s[t - off] : 0;
        __syncthreads();
        s[t] += x;
        __syncthreads();
    }
    if (t < nb) bsum[t] = s[t] - v;          // exclusive prefix
    if (t == 0) row_ptr[N] = E;
}

__global__ void k_scan_local(const int* __restrict__ deg, const int* __restrict__ bpre,
                             int* __restrict__ row_ptr, int n) {
    __shared__ int s[256];
    int t = threadIdx.x, i = blockIdx.x * 256 + t;
    int v = (i < n) ? deg[i] : 0;
    s[t] = v;
    __syncthreads();
    for (int off = 1; off < 256; off <<= 1) {
        int x = (t >= off) ? s[t - off] : 0;
        __syncthreads();
        s[t] += x;
        __syncthreads();
    }
    if (i < n) row_ptr[i] = bpre[blockIdx.x] + s[t] - v;   // exclusive
}

// bin edges into per-bucket regions (bucket = dst>>8); append via 391 cursors
__global__ void k_bin(const int* __restrict__ src, const int* __restrict__ dst,
                      const int* __restrict__ row_ptr, int* __restrict__ bcur,
                      int2* __restrict__ tmp, int E) {
    int e = blockIdx.x * blockDim.x + threadIdx.x;
    if (e >= E) return;
    int d = dst[e];
    int b = d >> 8;
    int base = row_ptr[b << 8];                 // bucket start (L2-hot)
    int pos = atomicAdd(&bcur[b], 1);
    tmp[base + pos] = make_int2(src[e], d);
}

// one block per bucket: scatter bucket edges to final CSR slots (LDS cursors);
// writes confined to the bucket's ~16KB eal window; eal packed src|ann<<17
__global__ __launch_bounds__(256) void k_fill2(
    const int2* __restrict__ tmp, const int* __restrict__ row_ptr,
    const int* __restrict__ ann, int* __restrict__ eal, int N) {
    __shared__ int cur[256];
    int b = blockIdx.x;
    int node0 = b << 8;
    int t = threadIdx.x;
    cur[t] = 0;
    __syncthreads();
    int beg = row_ptr[node0];
    int hi = node0 + 256; if (hi > N) hi = N;
    int end = row_ptr[hi];
    for (int i = beg + t; i < end; i += 256) {
        int2 sd = tmp[i];
        int pos = atomicAdd(&cur[sd.y & 255], 1);
        eal[row_ptr[sd.y] + pos] = sd.x | (ann[sd.x] << 17);
    }
}

union H16Chunk { float4 f4; __half2 h2[4]; };

// ---------- embW16 = emb @ W1 (fp32 in, fp16 out, V rows) ------------------
__global__ __launch_bounds__(256) void k_gemm_plain16(
    const float* __restrict__ x, const float* __restrict__ W,
    __half* __restrict__ out16, int n, int ntiles) {
    __shared__ float Wl[128 * 128];
    __shared__ float Xs[128 * 132];
    int tid = threadIdx.x;

    const float4* W4 = (const float4*)W;
    float4* Wl4 = (float4*)Wl;
    #pragma unroll
    for (int i = 0; i < 16; i++) Wl4[tid + i * 256] = W4[tid + i * 256];

    int c0 = (tid & 15) * 8;
    int r0 = (tid >> 4) * 8;
    int sr = tid >> 1;
    int sq = (tid & 1) * 16;
    const float4* x4p = (const float4*)x;

    for (int tile = blockIdx.x; tile < ntiles; tile += gridDim.x) {
        __syncthreads();
        {
            int grow = tile * 128 + sr;
            if (grow < n) {
                #pragma unroll
                for (int j = 0; j < 16; j++) {
                    int q = sq + j;
                    float4 v = x4p[(size_t)grow * 32 + q];
                    Xs[(q * 4 + 0) * 132 + sr] = v.x;
                    Xs[(q * 4 + 1) * 132 + sr] = v.y;
                    Xs[(q * 4 + 2) * 132 + sr] = v.z;
                    Xs[(q * 4 + 3) * 132 + sr] = v.w;
                }
            }
        }
        __syncthreads();

        float acc[8][8] = {};
        #pragma unroll 2
        for (int k = 0; k < 128; k++) {
            float4 xa = *(const float4*)&Xs[k * 132 + r0];
            float4 xb = *(const float4*)&Xs[k * 132 + r0 + 4];
            float4 wa = *(const float4*)&Wl[k * 128 + c0];
            float4 wb = *(const float4*)&Wl[k * 128 + c0 + 4];
            float xr[8] = {xa.x, xa.y, xa.z, xa.w, xb.x, xb.y, xb.z, xb.w};
            float wc[8] = {wa.x, wa.y, wa.z, wa.w, wb.x, wb.y, wb.z, wb.w};
            #pragma unroll
            for (int i = 0; i < 8; i++)
                #pragma unroll
                for (int j = 0; j < 8; j++)
                    acc[i][j] += xr[i] * wc[j];
        }

        int row0 = tile * 128;
        #pragma unroll
        for (int i = 0; i < 8; i++) {
            int r = row0 + r0 + i;
            if (r < n) {
                H16Chunk u;
                u.h2[0] = __floats2half2_rn(acc[i][0], acc[i][1]);
                u.h2[1] = __floats2half2_rn(acc[i][2], acc[i][3]);
                u.h2[2] = __floats2half2_rn(acc[i][4], acc[i][5]);
                u.h2[3] = __floats2half2_rn(acc[i][6], acc[i][7]);
                *(float4*)&out16[(size_t)r * 128 + c0] = u.f4;
            }
        }
    }
}

// ---------- g = x16 @ W (fp16 in, fp16 out, no epilogue), persistent -------
__global__ __launch_bounds__(256) void k_gemm16(
    const __half* __restrict__ x16, const float* __restrict__ W,
    __half* __restrict__ g16, int n, int ntiles) {
    __shared__ float Wl[128 * 128];
    __shared__ float Xs[128 * 132];
    int tid = threadIdx.x;

    const float4* W4 = (const float4*)W;
    float4* Wl4 = (float4*)Wl;
    #pragma unroll
    for (int i = 0; i < 16; i++) Wl4[tid + i * 256] = W4[tid + i * 256];

    int c0 = (tid & 15) * 8;
    int r0 = (tid >> 4) * 8;
    int sr = tid >> 1;
    int sq = (tid & 1) * 8;
    const float4* x4p = (const float4*)x16;

    float4 pf[8];
    int tile = blockIdx.x;
    if (tile < ntiles) {
        int grow = tile * 128 + sr;
        if (grow < n) {
            #pragma unroll
            for (int j = 0; j < 8; j++) pf[j] = x4p[(size_t)grow * 16 + sq + j];
        }
    }

    for (; tile < ntiles; tile += gridDim.x) {
        __syncthreads();
        {
            int grow = tile * 128 + sr;
            if (grow < n) {
                #pragma unroll
                for (int j = 0; j < 8; j++) {
                    H16Chunk u; u.f4 = pf[j];
                    int kb = (sq + j) * 8;
                    #pragma unroll
                    for (int i = 0; i < 4; i++) {
                        float2 t = __half22float2(u.h2[i]);
                        Xs[(kb + 2 * i + 0) * 132 + sr] = t.x;
                        Xs[(kb + 2 * i + 1) * 132 + sr] = t.y;
                    }
                }
            }
        }
        __syncthreads();

        int ntile = tile + gridDim.x;
        if (ntile < ntiles) {
            int grow = ntile * 128 + sr;
            if (grow < n) {
                #pragma unroll
                for (int j = 0; j < 8; j++) pf[j] = x4p[(size_t)grow * 16 + sq + j];
            }
        }

        float acc[8][8] = {};
        #pragma unroll 2
        for (int k = 0; k < 128; k++) {
            float4 xa = *(const float4*)&Xs[k * 132 + r0];
            float4 xb = *(const float4*)&Xs[k * 132 + r0 + 4];
            float4 wa = *(const float4*)&Wl[k * 128 + c0];
            float4 wb = *(const float4*)&Wl[k * 128 + c0 + 4];
            float xr[8] = {xa.x, xa.y, xa.z, xa.w, xb.x, xb.y, xb.z, xb.w};
            float wc[8] = {wa.x, wa.y, wa.z, wa.w, wb.x, wb.y, wb.z, wb.w};
            #pragma unroll
            for (int i = 0; i < 8; i++)
                #pragma unroll
                for (int j = 0; j < 8; j++)
                    acc[i][j] += xr[i] * wc[j];
        }

        int row0 = tile * 128;
        #pragma unroll
        for (int i = 0; i < 8; i++) {
            int r = row0 + r0 + i;
            if (r < n) {
                H16Chunk u;
                u.h2[0] = __floats2half2_rn(acc[i][0], acc[i][1]);
                u.h2[1] = __floats2half2_rn(acc[i][2], acc[i][3]);
                u.h2[2] = __floats2half2_rn(acc[i][4], acc[i][5]);
                u.h2[3] = __floats2half2_rn(acc[i][6], acc[i][7]);
                *(float4*)&g16[(size_t)r * 128 + c0] = u.f4;
            }
        }
    }
}

// ---------- unified agg over fp16 256B rows + fused epilogue ---------------
// SELY: row index = ann bits (>>17) and self row = tab[selfidx[v]] (layer 1);
// else row index = src bits (&SRC_MASK), self row = tab[v] (layers 2-3).
// out = relu(inv*(self + sum rows) + b) -> fp16 (OUT32=false) or fp32.
template<bool SELY, bool OUT32>
__global__ __launch_bounds__(256) void k_agg(
    const float4* __restrict__ tab, const int* __restrict__ selfidx,
    const int* __restrict__ row_ptr, const int* __restrict__ eal,
    const float4* __restrict__ bias4,
    __half* __restrict__ h16out, float* __restrict__ f32out, int n) {
    int v = blockIdx.x * 4 + (threadIdx.x >> 6);
    int lane = threadIdx.x & 63;
    int g = lane >> 4;           // group 0..3
    int q = lane & 15;           // 16B chunk within 256B row
    int beg = row_ptr[v], end = row_ptr[v + 1];
    int deg = end - beg;
    float acc[8] = {};

    #define ACCUM(raw) do { H16Chunk u; u.f4 = (raw);                          \
        float2 t0 = __half22float2(u.h2[0]); acc[0] += t0.x; acc[1] += t0.y;   \
        float2 t1 = __half22float2(u.h2[1]); acc[2] += t1.x; acc[3] += t1.y;   \
        float2 t2 = __half22float2(u.h2[2]); acc[4] += t2.x; acc[5] += t2.y;   \
        float2 t3 = __half22float2(u.h2[3]); acc[6] += t3.x; acc[7] += t3.y; } while (0)
    #define IDX(w) (SELY ? ((w) >> 17) : ((w) & SRC_MASK))

    if (g == 0) {
        int sr = SELY ? selfidx[v] : v;
        ACCUM(tab[(size_t)sr * 16 + q]);       // self term once
    }

    int quads = deg >> 2;
    int p = 0;
    for (; p + 4 <= quads; p += 4) {   // deg>=16: 16 rows in flight per wave
        int eb = beg + 4 * p + g;
        int w0 = eal[eb + 0], w1 = eal[eb + 4], w2 = eal[eb + 8], w3 = eal[eb + 12];
        float4 r0 = tab[(size_t)IDX(w0) * 16 + q], r1 = tab[(size_t)IDX(w1) * 16 + q];
        float4 r2 = tab[(size_t)IDX(w2) * 16 + q], r3 = tab[(size_t)IDX(w3) * 16 + q];
        ACCUM(r0); ACCUM(r1); ACCUM(r2); ACCUM(r3);
    }
    for (; p < quads; p++) ACCUM(tab[(size_t)IDX(eal[beg + 4 * p + g]) * 16 + q]);
    int tail = deg & 3;
    if (g < tail) ACCUM(tab[(size_t)IDX(eal[beg + 4 * quads + g]) * 16 + q]);
    #undef ACCUM
    #undef IDX

    #pragma unroll
    for (int j = 0; j < 8; j++) {
        acc[j] += __shfl_down(acc[j], 16, 64);   // g0+=g1, g2+=g3
        acc[j] += __shfl_down(acc[j], 32, 64);   // g0+=g2
    }
    if (g == 0) {
        float sc = 1.0f / (float)(deg + 1);
        float4 b0 = bias4[2 * q], b1 = bias4[2 * q + 1];
        float o[8];
        o[0] = fmaxf(acc[0] * sc + b0.x, 0.f);
        o[1] = fmaxf(acc[1] * sc + b0.y, 0.f);
        o[2] = fmaxf(acc[2] * sc + b0.z, 0.f);
        o[3] = fmaxf(acc[3] * sc + b0.w, 0.f);
        o[4] = fmaxf(acc[4] * sc + b1.x, 0.f);
        o[5] = fmaxf(acc[5] * sc + b1.y, 0.f);
        o[6] = fmaxf(acc[6] * sc + b1.z, 0.f);
        o[7] = fmaxf(acc[7] * sc + b1.w, 0.f);
        if (!OUT32) {
            H16Chunk u;
            u.h2[0] = __floats2half2_rn(o[0], o[1]);
            u.h2[1] = __floats2half2_rn(o[2], o[3]);
            u.h2[2] = __floats2half2_rn(o[4], o[5]);
            u.h2[3] = __floats2half2_rn(o[6], o[7]);
            *(float4*)&h16out[(size_t)v * 128 + q * 8] = u.f4;
        } else {
            *(float4*)&f32out[(size_t)v * 128 + q * 8]     = make_float4(o[0], o[1], o[2], o[3]);
            *(float4*)&f32out[(size_t)v * 128 + q * 8 + 4] = make_float4(o[4], o[5], o[6], o[7]);
        }
    }
}

extern "C" void kernel_launch(void* const* d_in, const int* in_sizes, int n_in,
                              void* d_out, int out_size, void* d_ws, size_t ws_size,
                              hipStream_t stream) {
    const int*   ann = (const int*)d_in[0];
    const int*   src = (const int*)d_in[1];
    const int*   dst = (const int*)d_in[2];
    const float* emb = (const float*)d_in[3];
    const float* Ws  = (const float*)d_in[4];
    const float* bs  = (const float*)d_in[5];
    float* out = (float*)d_out;

    const int N = in_sizes[0];          // 100000
    const int E = in_sizes[1];          // 1600000
    const int V = in_sizes[3] / D;      // 5000
    const int NB  = (N + 255) / 256;    // 391 (also bucket count)
    const int NT  = (N + 127) / 128;    // 782
    const int NTV = (V + 127) / 128;    // 40

    // ws (ints): deg[N] | row_ptr[N+4 pad] | bsum[512] | bcur[512]
    //            | tmp[int2 E] | eal[E] | hA16 [N*D f16] | gB16 [N*D f16]
    //            | embW16 [V*D f16]     (~72.5 MB)
    int*  deg     = (int*)d_ws;
    int*  row_ptr = deg + N;                       // N mult of 4
    int*  bsum    = row_ptr + ((N + 1 + 3) & ~3);
    int*  bcur    = bsum + 512;
    int2* tmp     = (int2*)(bcur + 512);
    int*  eal     = (int*)(tmp + E);
    __half* hA16  = (__half*)(eal + E);
    __half* gB16  = hA16 + (size_t)N * D;
    __half* embW16= gB16 + (size_t)N * D;

    // --- embW16 = emb @ W1 (tiny; independent of CSR) ---
    k_gemm_plain16<<<NTV, 256, 0, stream>>>(emb, Ws, embW16, V, NTV);

    // --- CSR build: count -> scan -> bin -> bucket-local fill ---
    hipMemsetAsync(deg, 0, (size_t)N * sizeof(int), stream);
    hipMemsetAsync(bcur, 0, 512 * sizeof(int), stream);
    k_count<<<(E + 255) / 256, 256, 0, stream>>>(dst, deg, E);
    k_bsum<<<NB, 256, 0, stream>>>(deg, bsum, N);
    k_scanb<<<1, 512, 0, stream>>>(bsum, NB, row_ptr, N, E);
    k_scan_local<<<NB, 256, 0, stream>>>(deg, bsum, row_ptr, N);
    k_bin<<<(E + 255) / 256, 256, 0, stream>>>(src, dst, row_ptr, bcur, tmp, E);
    k_fill2<<<NB, 256, 0, stream>>>(tmp, row_ptr, ann, eal, N);

    // --- layer 1: fused agg over embW16 (ann-indexed) -> h1 (fp16) ---
    k_agg<true, false><<<N / 4, 256, 0, stream>>>(
        (const float4*)embW16, ann, row_ptr, eal, (const float4*)bs,
        hA16, nullptr, N);

    // --- layer 2: g1 = h1@W2 (fp16); fused agg -> h2 (fp16) ---
    k_gemm16<<<256, 256, 0, stream>>>(hA16, Ws + (size_t)D * D, gB16, N, NT);
    k_agg<false, false><<<N / 4, 256, 0, stream>>>(
        (const float4*)gB16, nullptr, row_ptr, eal, (const float4*)(bs + D),
        hA16, nullptr, N);

    // --- layer 3: g2 = h2@W3 (fp16); fused agg -> out (fp32) ---
    k_gemm16<<<256, 256, 0, stream>>>(hA16, Ws + (size_t)2 * D * D, gB16, N, NT);
    k_agg<false, true><<<N / 4, 256, 0, stream>>>(
        (const float4*)gB16, nullptr, row_ptr, eal, (const float4*)(bs + 2 * D),
        nullptr, out, N);
}

// Round 11
// 584.974 us; speedup vs baseline: 1.8351x; 1.8351x over previous
//
#include <hip/hip_runtime.h>
#include <hip/hip_fp16.h>

// Graph_NN: 3-layer SAGE (gcn aggregator), N=100000, E=1600000, D=128, fp32.
// R11 = R9 fill (direct int2 scatter, 87us measured; R10's 391-cursor binning
// hit atomic contention: 557us at 0.14 TB/s) + R10's verified unified agg and
// fp16 embW (layer-1 table 1.28MB = per-XCD-L2-resident, 4 rows/instr).
// Layers 2-3 agg pinned at ~4 TB/s random-row L2-miss ceiling (R9 measured).
// Final fp32 out written nontemporal (read-never; keep g-table in L2).

#define D 128

typedef float f32x4 __attribute__((ext_vector_type(4)));

// ---------- CSR build ----------
__global__ void k_count(const int* __restrict__ dst, int* __restrict__ deg, int E) {
    int e = blockIdx.x * blockDim.x + threadIdx.x;
    if (e < E) atomicAdd(&deg[dst[e]], 1);
}

__global__ void k_bsum(const int* __restrict__ deg, int* __restrict__ bsum, int n) {
    __shared__ int s[256];
    int t = threadIdx.x, i = blockIdx.x * 256 + t;
    s[t] = (i < n) ? deg[i] : 0;
    __syncthreads();
    for (int off = 128; off > 0; off >>= 1) { if (t < off) s[t] += s[t + off]; __syncthreads(); }
    if (t == 0) bsum[blockIdx.x] = s[0];
}

__global__ void k_scanb(int* __restrict__ bsum, int nb, int* __restrict__ row_ptr, int N, int E) {
    __shared__ int s[512];
    int t = threadIdx.x;
    int v = (t < nb) ? bsum[t] : 0;
    s[t] = v;
    __syncthreads();
    for (int off = 1; off < 512; off <<= 1) {
        int x = (t >= off) ? s[t - off] : 0;
        __syncthreads();
        s[t] += x;
        __syncthreads();
    }
    if (t < nb) bsum[t] = s[t] - v;          // exclusive prefix
    if (t == 0) row_ptr[N] = E;
}

// writes exclusive row_ptr AND zeroes deg (it becomes the fill cursor)
__global__ void k_scan_local(int* __restrict__ deg, const int* __restrict__ bpre,
                             int* __restrict__ row_ptr, int n) {
    __shared__ int s[256];
    int t = threadIdx.x, i = blockIdx.x * 256 + t;
    int v = (i < n) ? deg[i] : 0;
    s[t] = v;
    __syncthreads();
    for (int off = 1; off < 256; off <<= 1) {
        int x = (t >= off) ? s[t - off] : 0;
        __syncthreads();
        s[t] += x;
        __syncthreads();
    }
    if (i < n) {
        row_ptr[i] = bpre[blockIdx.x] + s[t] - v;   // exclusive
        deg[i] = 0;                                  // reset cursor for k_fill
    }
}

// fill eal[pos] = (src, ann[src]) grouped by dst — single 8B scattered write
// (per-node cursors: ~16 hits each, no contention; R8 showed 4B-only is SLOWER)
__global__ void k_fill(const int* __restrict__ src, const int* __restrict__ dst,
                       const int* __restrict__ ann, const int* __restrict__ row_ptr,
                       int* __restrict__ cur, int2* __restrict__ eal, int E) {
    int e = blockIdx.x * blockDim.x + threadIdx.x;
    if (e >= E) return;
    int d = dst[e];
    int s = src[e];
    int pos = atomicAdd(&cur[d], 1);
    eal[row_ptr[d] + pos] = make_int2(s, ann[s]);
}

union H16Chunk { float4 f4; __half2 h2[4]; };

// ---------- embW16 = emb @ W1 (fp32 in, fp16 out, V rows) ------------------
__global__ __launch_bounds__(256) void k_gemm_plain16(
    const float* __restrict__ x, const float* __restrict__ W,
    __half* __restrict__ out16, int n, int ntiles) {
    __shared__ float Wl[128 * 128];
    __shared__ float Xs[128 * 132];
    int tid = threadIdx.x;

    const float4* W4 = (const float4*)W;
    float4* Wl4 = (float4*)Wl;
    #pragma unroll
    for (int i = 0; i < 16; i++) Wl4[tid + i * 256] = W4[tid + i * 256];

    int c0 = (tid & 15) * 8;
    int r0 = (tid >> 4) * 8;
    int sr = tid >> 1;
    int sq = (tid & 1) * 16;
    const float4* x4p = (const float4*)x;

    for (int tile = blockIdx.x; tile < ntiles; tile += gridDim.x) {
        __syncthreads();
        {
            int grow = tile * 128 + sr;
            if (grow < n) {
                #pragma unroll
                for (int j = 0; j < 16; j++) {
                    int q = sq + j;
                    float4 v = x4p[(size_t)grow * 32 + q];
                    Xs[(q * 4 + 0) * 132 + sr] = v.x;
                    Xs[(q * 4 + 1) * 132 + sr] = v.y;
                    Xs[(q * 4 + 2) * 132 + sr] = v.z;
                    Xs[(q * 4 + 3) * 132 + sr] = v.w;
                }
            }
        }
        __syncthreads();

        float acc[8][8] = {};
        #pragma unroll 2
        for (int k = 0; k < 128; k++) {
            float4 xa = *(const float4*)&Xs[k * 132 + r0];
            float4 xb = *(const float4*)&Xs[k * 132 + r0 + 4];
            float4 wa = *(const float4*)&Wl[k * 128 + c0];
            float4 wb = *(const float4*)&Wl[k * 128 + c0 + 4];
            float xr[8] = {xa.x, xa.y, xa.z, xa.w, xb.x, xb.y, xb.z, xb.w};
            float wc[8] = {wa.x, wa.y, wa.z, wa.w, wb.x, wb.y, wb.z, wb.w};
            #pragma unroll
            for (int i = 0; i < 8; i++)
                #pragma unroll
                for (int j = 0; j < 8; j++)
                    acc[i][j] += xr[i] * wc[j];
        }

        int row0 = tile * 128;
        #pragma unroll
        for (int i = 0; i < 8; i++) {
            int r = row0 + r0 + i;
            if (r < n) {
                H16Chunk u;
                u.h2[0] = __floats2half2_rn(acc[i][0], acc[i][1]);
                u.h2[1] = __floats2half2_rn(acc[i][2], acc[i][3]);
                u.h2[2] = __floats2half2_rn(acc[i][4], acc[i][5]);
                u.h2[3] = __floats2half2_rn(acc[i][6], acc[i][7]);
                *(float4*)&out16[(size_t)r * 128 + c0] = u.f4;
            }
        }
    }
}

// ---------- g = x16 @ W (fp16 in, fp16 out, no epilogue), persistent -------
__global__ __launch_bounds__(256) void k_gemm16(
    const __half* __restrict__ x16, const float* __restrict__ W,
    __half* __restrict__ g16, int n, int ntiles) {
    __shared__ float Wl[128 * 128];
    __shared__ float Xs[128 * 132];
    int tid = threadIdx.x;

    const float4* W4 = (const float4*)W;
    float4* Wl4 = (float4*)Wl;
    #pragma unroll
    for (int i = 0; i < 16; i++) Wl4[tid + i * 256] = W4[tid + i * 256];

    int c0 = (tid & 15) * 8;
    int r0 = (tid >> 4) * 8;
    int sr = tid >> 1;
    int sq = (tid & 1) * 8;
    const float4* x4p = (const float4*)x16;

    float4 pf[8];
    int tile = blockIdx.x;
    if (tile < ntiles) {
        int grow = tile * 128 + sr;
        if (grow < n) {
            #pragma unroll
            for (int j = 0; j < 8; j++) pf[j] = x4p[(size_t)grow * 16 + sq + j];
        }
    }

    for (; tile < ntiles; tile += gridDim.x) {
        __syncthreads();
        {
            int grow = tile * 128 + sr;
            if (grow < n) {
                #pragma unroll
                for (int j = 0; j < 8; j++) {
                    H16Chunk u; u.f4 = pf[j];
                    int kb = (sq + j) * 8;
                    #pragma unroll
                    for (int i = 0; i < 4; i++) {
                        float2 t = __half22float2(u.h2[i]);
                        Xs[(kb + 2 * i + 0) * 132 + sr] = t.x;
                        Xs[(kb + 2 * i + 1) * 132 + sr] = t.y;
                    }
                }
            }
        }
        __syncthreads();

        int ntile = tile + gridDim.x;
        if (ntile < ntiles) {
            int grow = ntile * 128 + sr;
            if (grow < n) {
                #pragma unroll
                for (int j = 0; j < 8; j++) pf[j] = x4p[(size_t)grow * 16 + sq + j];
            }
        }

        float acc[8][8] = {};
        #pragma unroll 2
        for (int k = 0; k < 128; k++) {
            float4 xa = *(const float4*)&Xs[k * 132 + r0];
            float4 xb = *(const float4*)&Xs[k * 132 + r0 + 4];
            float4 wa = *(const float4*)&Wl[k * 128 + c0];
            float4 wb = *(const float4*)&Wl[k * 128 + c0 + 4];
            float xr[8] = {xa.x, xa.y, xa.z, xa.w, xb.x, xb.y, xb.z, xb.w};
            float wc[8] = {wa.x, wa.y, wa.z, wa.w, wb.x, wb.y, wb.z, wb.w};
            #pragma unroll
            for (int i = 0; i < 8; i++)
                #pragma unroll
                for (int j = 0; j < 8; j++)
                    acc[i][j] += xr[i] * wc[j];
        }

        int row0 = tile * 128;
        #pragma unroll
        for (int i = 0; i < 8; i++) {
            int r = row0 + r0 + i;
            if (r < n) {
                H16Chunk u;
                u.h2[0] = __floats2half2_rn(acc[i][0], acc[i][1]);
                u.h2[1] = __floats2half2_rn(acc[i][2], acc[i][3]);
                u.h2[2] = __floats2half2_rn(acc[i][4], acc[i][5]);
                u.h2[3] = __floats2half2_rn(acc[i][6], acc[i][7]);
                *(float4*)&g16[(size_t)r * 128 + c0] = u.f4;
            }
        }
    }
}

// ---------- unified agg over fp16 256B rows + fused epilogue ---------------
// SELY: neighbor row = eal.y (ann of src), self row = selfidx[v] (layer 1);
// else neighbor row = eal.x (src),        self row = v        (layers 2-3).
// out = relu(inv*(self + sum rows) + b) -> fp16 (OUT32=false) or fp32 nt.
template<bool SELY, bool OUT32>
__global__ __launch_bounds__(256) void k_agg(
    const float4* __restrict__ tab, const int* __restrict__ selfidx,
    const int* __restrict__ row_ptr, const int2* __restrict__ eal,
    const float4* __restrict__ bias4,
    __half* __restrict__ h16out, float* __restrict__ f32out, int n) {
    int v = blockIdx.x * 4 + (threadIdx.x >> 6);
    int lane = threadIdx.x & 63;
    int g = lane >> 4;           // group 0..3
    int q = lane & 15;           // 16B chunk within 256B row
    int beg = row_ptr[v], end = row_ptr[v + 1];
    int deg = end - beg;
    float acc[8] = {};

    #define ACCUM(raw) do { H16Chunk u; u.f4 = (raw);                          \
        float2 t0 = __half22float2(u.h2[0]); acc[0] += t0.x; acc[1] += t0.y;   \
        float2 t1 = __half22float2(u.h2[1]); acc[2] += t1.x; acc[3] += t1.y;   \
        float2 t2 = __half22float2(u.h2[2]); acc[4] += t2.x; acc[5] += t2.y;   \
        float2 t3 = __half22float2(u.h2[3]); acc[6] += t3.x; acc[7] += t3.y; } while (0)
    #define IDX(w) (SELY ? (w).y : (w).x)

    if (g == 0) {
        int sr = SELY ? selfidx[v] : v;
        ACCUM(tab[(size_t)sr * 16 + q]);       // self term once
    }

    int quads = deg >> 2;
    int p = 0;
    for (; p + 4 <= quads; p += 4) {   // deg>=16: 16 rows in flight per wave
        int eb = beg + 4 * p + g;
        int2 w0 = eal[eb + 0], w1 = eal[eb + 4], w2 = eal[eb + 8], w3 = eal[eb + 12];
        float4 r0 = tab[(size_t)IDX(w0) * 16 + q], r1 = tab[(size_t)IDX(w1) * 16 + q];
        float4 r2 = tab[(size_t)IDX(w2) * 16 + q], r3 = tab[(size_t)IDX(w3) * 16 + q];
        ACCUM(r0); ACCUM(r1); ACCUM(r2); ACCUM(r3);
    }
    for (; p < quads; p++) ACCUM(tab[(size_t)IDX(eal[beg + 4 * p + g]) * 16 + q]);
    int tail = deg & 3;
    if (g < tail) ACCUM(tab[(size_t)IDX(eal[beg + 4 * quads + g]) * 16 + q]);
    #undef ACCUM
    #undef IDX

    #pragma unroll
    for (int j = 0; j < 8; j++) {
        acc[j] += __shfl_down(acc[j], 16, 64);   // g0+=g1, g2+=g3
        acc[j] += __shfl_down(acc[j], 32, 64);   // g0+=g2
    }
    if (g == 0) {
        float sc = 1.0f / (float)(deg + 1);
        float4 b0 = bias4[2 * q], b1 = bias4[2 * q + 1];
        float o[8];
        o[0] = fmaxf(acc[0] * sc + b0.x, 0.f);
        o[1] = fmaxf(acc[1] * sc + b0.y, 0.f);
        o[2] = fmaxf(acc[2] * sc + b0.z, 0.f);
        o[3] = fmaxf(acc[3] * sc + b0.w, 0.f);
        o[4] = fmaxf(acc[4] * sc + b1.x, 0.f);
        o[5] = fmaxf(acc[5] * sc + b1.y, 0.f);
        o[6] = fmaxf(acc[6] * sc + b1.z, 0.f);
        o[7] = fmaxf(acc[7] * sc + b1.w, 0.f);
        if (!OUT32) {
            H16Chunk u;
            u.h2[0] = __floats2half2_rn(o[0], o[1]);
            u.h2[1] = __floats2half2_rn(o[2], o[3]);
            u.h2[2] = __floats2half2_rn(o[4], o[5]);
            u.h2[3] = __floats2half2_rn(o[6], o[7]);
            *(float4*)&h16out[(size_t)v * 128 + q * 8] = u.f4;
        } else {
            // nontemporal: final output is never re-read; keep g-table in L2
            f32x4 a = {o[0], o[1], o[2], o[3]};
            f32x4 b = {o[4], o[5], o[6], o[7]};
            __builtin_nontemporal_store(a, (f32x4*)&f32out[(size_t)v * 128 + q * 8]);
            __builtin_nontemporal_store(b, (f32x4*)&f32out[(size_t)v * 128 + q * 8 + 4]);
        }
    }
}

extern "C" void kernel_launch(void* const* d_in, const int* in_sizes, int n_in,
                              void* d_out, int out_size, void* d_ws, size_t ws_size,
                              hipStream_t stream) {
    const int*   ann = (const int*)d_in[0];
    const int*   src = (const int*)d_in[1];
    const int*   dst = (const int*)d_in[2];
    const float* emb = (const float*)d_in[3];
    const float* Ws  = (const float*)d_in[4];
    const float* bs  = (const float*)d_in[5];
    float* out = (float*)d_out;

    const int N = in_sizes[0];          // 100000
    const int E = in_sizes[1];          // 1600000
    const int V = in_sizes[3] / D;      // 5000
    const int NB  = (N + 255) / 256;    // 391
    const int NT  = (N + 127) / 128;    // 782
    const int NTV = (V + 127) / 128;    // 40

    // ws: deg[N] | row_ptr[N+1 pad] | bsum[512] | eal[int2 E]
    //     | hA16 [N*D f16] | gB16 [N*D f16] | embW16 [V*D f16]  (~65 MB)
    int*  deg     = (int*)d_ws;
    int*  row_ptr = deg + N;                       // N mult of 4
    int*  bsum    = row_ptr + ((N + 1 + 3) & ~3);
    int2* eal     = (int2*)(bsum + 512);
    __half* hA16  = (__half*)(eal + E);
    __half* gB16  = hA16 + (size_t)N * D;
    __half* embW16= gB16 + (size_t)N * D;

    // --- embW16 = emb @ W1 (tiny; independent of CSR) ---
    k_gemm_plain16<<<NTV, 256, 0, stream>>>(emb, Ws, embW16, V, NTV);

    // --- CSR build: count -> scan (scan_local also zeroes deg) -> fill ---
    hipMemsetAsync(deg, 0, (size_t)N * sizeof(int), stream);
    k_count<<<(E + 255) / 256, 256, 0, stream>>>(dst, deg, E);
    k_bsum<<<NB, 256, 0, stream>>>(deg, bsum, N);
    k_scanb<<<1, 512, 0, stream>>>(bsum, NB, row_ptr, N, E);
    k_scan_local<<<NB, 256, 0, stream>>>(deg, bsum, row_ptr, N);
    k_fill<<<(E + 255) / 256, 256, 0, stream>>>(src, dst, ann, row_ptr, deg, eal, E);

    // --- layer 1: fused agg over embW16 (ann-indexed, L2-resident) -> h1 ---
    k_agg<true, false><<<N / 4, 256, 0, stream>>>(
        (const float4*)embW16, ann, row_ptr, eal, (const float4*)bs,
        hA16, nullptr, N);

    // --- layer 2: g1 = h1@W2 (fp16); fused agg -> h2 (fp16) ---
    k_gemm16<<<256, 256, 0, stream>>>(hA16, Ws + (size_t)D * D, gB16, N, NT);
    k_agg<false, false><<<N / 4, 256, 0, stream>>>(
        (const float4*)gB16, nullptr, row_ptr, eal, (const float4*)(bs + D),
        hA16, nullptr, N);

    // --- layer 3: g2 = h2@W3 (fp16); fused agg -> out (fp32, nontemporal) ---
    k_gemm16<<<256, 256, 0, stream>>>(hA16, Ws + (size_t)2 * D * D, gB16, N, NT);
    k_agg<false, true><<<N / 4, 256, 0, stream>>>(
        (const float4*)gB16, nullptr, row_ptr, eal, (const float4*)(bs + 2 * D),
        nullptr, out, N);
}

// Round 12
// 489.145 us; speedup vs baseline: 2.1946x; 1.1959x over previous
//
#include <hip/hip_runtime.h>
#include <hip/hip_fp16.h>

// Graph_NN: 3-layer SAGE (gcn aggregator), N=100000, E=1600000, D=128, fp32.
// R12 = R11 + GEMMs moved to MFMA (mfma_f32_16x16x32_f16):
//   - x already fp16; W cast to fp16 (err ~5e-6 vs 1.27e-4 budget).
//   - per block: W staged once in FRAGMENT order in LDS, all 32 B-frags
//     hoisted to registers; per 64-row tile: stage x, 4 ksteps x 8 col-tiles
//     MFMA, epilogue via LDS transpose -> coalesced fp16 stores.
//   - emb pre-cast fp16 so the same kernel does embW (plain fp32 GEMM gone).
// Aggs (84us @3.9TB/s random-gather ceiling) and fill (~82us line-alloc
// ceiling) unchanged from R11 — measured rooflines.

#define D 128

typedef float f32x4 __attribute__((ext_vector_type(4)));
typedef _Float16 f16x8 __attribute__((ext_vector_type(8)));

// ---------- CSR build ----------
__global__ void k_count(const int* __restrict__ dst, int* __restrict__ deg, int E) {
    int e = blockIdx.x * blockDim.x + threadIdx.x;
    if (e < E) atomicAdd(&deg[dst[e]], 1);
}

__global__ void k_bsum(const int* __restrict__ deg, int* __restrict__ bsum, int n) {
    __shared__ int s[256];
    int t = threadIdx.x, i = blockIdx.x * 256 + t;
    s[t] = (i < n) ? deg[i] : 0;
    __syncthreads();
    for (int off = 128; off > 0; off >>= 1) { if (t < off) s[t] += s[t + off]; __syncthreads(); }
    if (t == 0) bsum[blockIdx.x] = s[0];
}

__global__ void k_scanb(int* __restrict__ bsum, int nb, int* __restrict__ row_ptr, int N, int E) {
    __shared__ int s[512];
    int t = threadIdx.x;
    int v = (t < nb) ? bsum[t] : 0;
    s[t] = v;
    __syncthreads();
    for (int off = 1; off < 512; off <<= 1) {
        int x = (t >= off) ? s[t - off] : 0;
        __syncthreads();
        s[t] += x;
        __syncthreads();
    }
    if (t < nb) bsum[t] = s[t] - v;          // exclusive prefix
    if (t == 0) row_ptr[N] = E;
}

// writes exclusive row_ptr AND zeroes deg (it becomes the fill cursor)
__global__ void k_scan_local(int* __restrict__ deg, const int* __restrict__ bpre,
                             int* __restrict__ row_ptr, int n) {
    __shared__ int s[256];
    int t = threadIdx.x, i = blockIdx.x * 256 + t;
    int v = (i < n) ? deg[i] : 0;
    s[t] = v;
    __syncthreads();
    for (int off = 1; off < 256; off <<= 1) {
        int x = (t >= off) ? s[t - off] : 0;
        __syncthreads();
        s[t] += x;
        __syncthreads();
    }
    if (i < n) {
        row_ptr[i] = bpre[blockIdx.x] + s[t] - v;   // exclusive
        deg[i] = 0;                                  // reset cursor for k_fill
    }
}

// fill eal[pos] = (src, ann[src]) grouped by dst — single 8B scattered write
__global__ void k_fill(const int* __restrict__ src, const int* __restrict__ dst,
                       const int* __restrict__ ann, const int* __restrict__ row_ptr,
                       int* __restrict__ cur, int2* __restrict__ eal, int E) {
    int e = blockIdx.x * blockDim.x + threadIdx.x;
    if (e >= E) return;
    int d = dst[e];
    int s = src[e];
    int pos = atomicAdd(&cur[d], 1);
    eal[row_ptr[d] + pos] = make_int2(s, ann[s]);
}

union H16Chunk { float4 f4; __half2 h2[4]; __half h[8]; };

// ---------- fp32 -> fp16 cast (for emb) ----------
__global__ void k_h16(const float* __restrict__ x, __half* __restrict__ y, int n8) {
    int i = blockIdx.x * blockDim.x + threadIdx.x;
    if (i >= n8) return;
    const float4* p = (const float4*)x;
    float4 a = p[2 * i], b = p[2 * i + 1];
    H16Chunk u;
    u.h2[0] = __floats2half2_rn(a.x, a.y);
    u.h2[1] = __floats2half2_rn(a.z, a.w);
    u.h2[2] = __floats2half2_rn(b.x, b.y);
    u.h2[3] = __floats2half2_rn(b.z, b.w);
    *(float4*)&y[8 * i] = u.f4;
}

// ---------- g16 = x16 @ W via MFMA (fp16 in/out, fp32 W cast to fp16) ------
// 256 thr = 4 waves; wave w owns rows [w*16, w*16+16) of each 64-row tile.
// W staged once per block in B-fragment order; 32 B-frags held in VGPRs.
// Layouts (verified, learn_hip m89/m120): A[m=lane&15][k=quad*8+j],
// B[n=lane&15][k=quad*8+j], C/D col=lane&15 row=quad*4+reg.
#define XT_LD 136   // halfs per row: 272B stride -> 16B aligned, conflict-free
__global__ __launch_bounds__(256) void k_gemm_mfma(
    const __half* __restrict__ x16, const float* __restrict__ W,
    __half* __restrict__ g16, int n, int ntiles) {
    __shared__ __half Bf[8 * 4 * 64 * 8];   // 32 KB, fragment order
    __shared__ __half Xt[64 * XT_LD];       // 17 KB, x tile / out stage
    int tid = threadIdx.x;
    int lane = tid & 63;
    int wv = tid >> 6;

    // stage W as fp16 B-fragments: entry (nt,ks,l) holds 8 halfs
    for (int idx = tid; idx < 8 * 4 * 64; idx += 256) {
        int l = idx & 63, ks = (idx >> 6) & 3, nt = idx >> 8;
        int kq = (l >> 4) * 8;
        int col = nt * 16 + (l & 15);
        H16Chunk u;
        #pragma unroll
        for (int j = 0; j < 8; j++)
            u.h[j] = __float2half(W[(ks * 32 + kq + j) * 128 + col]);
        *(float4*)&Bf[idx * 8] = u.f4;
    }
    __syncthreads();

    f16x8 breg[8][4];
    #pragma unroll
    for (int nt = 0; nt < 8; nt++)
        #pragma unroll
        for (int ks = 0; ks < 4; ks++)
            breg[nt][ks] = *(f16x8*)&Bf[((nt * 4 + ks) * 64 + lane) * 8];

    int srow = tid >> 2;            // staging row 0..63
    int sc = (tid & 3) * 32;        // staging col base (halfs)
    int m = lane & 15, quad = lane >> 4;

    for (int tile = blockIdx.x; tile < ntiles; tile += gridDim.x) {
        int row0 = tile * 64;
        __syncthreads();            // Xt free
        {
            int gr = row0 + srow;
            if (gr >= n) gr = n - 1;              // clamp; stores guarded below
            const float4* xp = (const float4*)&x16[(size_t)gr * 128 + sc];
            float4 v0 = xp[0], v1 = xp[1], v2 = xp[2], v3 = xp[3];
            float4* xd = (float4*)&Xt[srow * XT_LD + sc];
            xd[0] = v0; xd[1] = v1; xd[2] = v2; xd[3] = v3;
        }
        __syncthreads();

        f32x4 acc[8];
        #pragma unroll
        for (int nt = 0; nt < 8; nt++) acc[nt] = (f32x4){0.f, 0.f, 0.f, 0.f};
        #pragma unroll
        for (int ks = 0; ks < 4; ks++) {
            f16x8 a = *(f16x8*)&Xt[(wv * 16 + m) * XT_LD + ks * 32 + quad * 8];
            #pragma unroll
            for (int nt = 0; nt < 8; nt++)
                acc[nt] = __builtin_amdgcn_mfma_f32_16x16x32_f16(a, breg[nt][ks], acc[nt], 0, 0, 0);
        }
        __syncthreads();            // done reading Xt; reuse for output
        #pragma unroll
        for (int nt = 0; nt < 8; nt++)
            #pragma unroll
            for (int r = 0; r < 4; r++)
                Xt[(wv * 16 + quad * 4 + r) * XT_LD + nt * 16 + m] = __float2half(acc[nt][r]);
        __syncthreads();
        {
            int gr = row0 + srow;
            if (gr < n) {
                float4* gp = (float4*)&g16[(size_t)gr * 128 + sc];
                float4* xs = (float4*)&Xt[srow * XT_LD + sc];
                gp[0] = xs[0]; gp[1] = xs[1]; gp[2] = xs[2]; gp[3] = xs[3];
            }
        }
    }
}

// ---------- unified agg over fp16 256B rows + fused epilogue ---------------
// SELY: neighbor row = eal.y (ann of src), self row = selfidx[v] (layer 1);
// else neighbor row = eal.x (src),        self row = v        (layers 2-3).
template<bool SELY, bool OUT32>
__global__ __launch_bounds__(256) void k_agg(
    const float4* __restrict__ tab, const int* __restrict__ selfidx,
    const int* __restrict__ row_ptr, const int2* __restrict__ eal,
    const float4* __restrict__ bias4,
    __half* __restrict__ h16out, float* __restrict__ f32out, int n) {
    int v = blockIdx.x * 4 + (threadIdx.x >> 6);
    int lane = threadIdx.x & 63;
    int g = lane >> 4;           // group 0..3
    int q = lane & 15;           // 16B chunk within 256B row
    int beg = row_ptr[v], end = row_ptr[v + 1];
    int deg = end - beg;
    float acc[8] = {};

    #define ACCUM(raw) do { H16Chunk u; u.f4 = (raw);                          \
        float2 t0 = __half22float2(u.h2[0]); acc[0] += t0.x; acc[1] += t0.y;   \
        float2 t1 = __half22float2(u.h2[1]); acc[2] += t1.x; acc[3] += t1.y;   \
        float2 t2 = __half22float2(u.h2[2]); acc[4] += t2.x; acc[5] += t2.y;   \
        float2 t3 = __half22float2(u.h2[3]); acc[6] += t3.x; acc[7] += t3.y; } while (0)
    #define IDX(w) (SELY ? (w).y : (w).x)

    if (g == 0) {
        int sr = SELY ? selfidx[v] : v;
        ACCUM(tab[(size_t)sr * 16 + q]);       // self term once
    }

    int quads = deg >> 2;
    int p = 0;
    for (; p + 4 <= quads; p += 4) {   // deg>=16: 16 rows in flight per wave
        int eb = beg + 4 * p + g;
        int2 w0 = eal[eb + 0], w1 = eal[eb + 4], w2 = eal[eb + 8], w3 = eal[eb + 12];
        float4 r0 = tab[(size_t)IDX(w0) * 16 + q], r1 = tab[(size_t)IDX(w1) * 16 + q];
        float4 r2 = tab[(size_t)IDX(w2) * 16 + q], r3 = tab[(size_t)IDX(w3) * 16 + q];
        ACCUM(r0); ACCUM(r1); ACCUM(r2); ACCUM(r3);
    }
    for (; p < quads; p++) ACCUM(tab[(size_t)IDX(eal[beg + 4 * p + g]) * 16 + q]);
    int tail = deg & 3;
    if (g < tail) ACCUM(tab[(size_t)IDX(eal[beg + 4 * quads + g]) * 16 + q]);
    #undef ACCUM
    #undef IDX

    #pragma unroll
    for (int j = 0; j < 8; j++) {
        acc[j] += __shfl_down(acc[j], 16, 64);   // g0+=g1, g2+=g3
        acc[j] += __shfl_down(acc[j], 32, 64);   // g0+=g2
    }
    if (g == 0) {
        float sc = 1.0f / (float)(deg + 1);
        float4 b0 = bias4[2 * q], b1 = bias4[2 * q + 1];
        float o[8];
        o[0] = fmaxf(acc[0] * sc + b0.x, 0.f);
        o[1] = fmaxf(acc[1] * sc + b0.y, 0.f);
        o[2] = fmaxf(acc[2] * sc + b0.z, 0.f);
        o[3] = fmaxf(acc[3] * sc + b0.w, 0.f);
        o[4] = fmaxf(acc[4] * sc + b1.x, 0.f);
        o[5] = fmaxf(acc[5] * sc + b1.y, 0.f);
        o[6] = fmaxf(acc[6] * sc + b1.z, 0.f);
        o[7] = fmaxf(acc[7] * sc + b1.w, 0.f);
        if (!OUT32) {
            H16Chunk u;
            u.h2[0] = __floats2half2_rn(o[0], o[1]);
            u.h2[1] = __floats2half2_rn(o[2], o[3]);
            u.h2[2] = __floats2half2_rn(o[4], o[5]);
            u.h2[3] = __floats2half2_rn(o[6], o[7]);
            *(float4*)&h16out[(size_t)v * 128 + q * 8] = u.f4;
        } else {
            f32x4 a = {o[0], o[1], o[2], o[3]};
            f32x4 b = {o[4], o[5], o[6], o[7]};
            __builtin_nontemporal_store(a, (f32x4*)&f32out[(size_t)v * 128 + q * 8]);
            __builtin_nontemporal_store(b, (f32x4*)&f32out[(size_t)v * 128 + q * 8 + 4]);
        }
    }
}

extern "C" void kernel_launch(void* const* d_in, const int* in_sizes, int n_in,
                              void* d_out, int out_size, void* d_ws, size_t ws_size,
                              hipStream_t stream) {
    const int*   ann = (const int*)d_in[0];
    const int*   src = (const int*)d_in[1];
    const int*   dst = (const int*)d_in[2];
    const float* emb = (const float*)d_in[3];
    const float* Ws  = (const float*)d_in[4];
    const float* bs  = (const float*)d_in[5];
    float* out = (float*)d_out;

    const int N = in_sizes[0];          // 100000
    const int E = in_sizes[1];          // 1600000
    const int V = in_sizes[3] / D;      // 5000
    const int NB   = (N + 255) / 256;   // 391
    const int NT64 = (N + 63) / 64;     // 1563 MFMA row tiles
    const int VT64 = (V + 63) / 64;     // 79

    // ws: deg[N] | row_ptr[N+1 pad] | bsum[512] | eal[int2 E]
    //     | hA16 [N*D] | gB16 [N*D] | embW16 [V*D] | emb16 [V*D]   (~66 MB)
    int*  deg     = (int*)d_ws;
    int*  row_ptr = deg + N;                       // N mult of 4
    int*  bsum    = row_ptr + ((N + 1 + 3) & ~3);
    int2* eal     = (int2*)(bsum + 512);
    __half* hA16  = (__half*)(eal + E);
    __half* gB16  = hA16 + (size_t)N * D;
    __half* embW16= gB16 + (size_t)N * D;
    __half* emb16 = embW16 + (size_t)V * D;

    // --- emb -> fp16; embW16 = emb16 @ W1 (MFMA; independent of CSR) ---
    k_h16<<<(V * D / 8 + 255) / 256, 256, 0, stream>>>(emb, emb16, V * D / 8);
    k_gemm_mfma<<<VT64, 256, 0, stream>>>(emb16, Ws, embW16, V, VT64);

    // --- CSR build: count -> scan (scan_local also zeroes deg) -> fill ---
    hipMemsetAsync(deg, 0, (size_t)N * sizeof(int), stream);
    k_count<<<(E + 255) / 256, 256, 0, stream>>>(dst, deg, E);
    k_bsum<<<NB, 256, 0, stream>>>(deg, bsum, N);
    k_scanb<<<1, 512, 0, stream>>>(bsum, NB, row_ptr, N, E);
    k_scan_local<<<NB, 256, 0, stream>>>(deg, bsum, row_ptr, N);
    k_fill<<<(E + 255) / 256, 256, 0, stream>>>(src, dst, ann, row_ptr, deg, eal, E);

    // --- layer 1: fused agg over embW16 (ann-indexed, L2-resident) -> h1 ---
    k_agg<true, false><<<N / 4, 256, 0, stream>>>(
        (const float4*)embW16, ann, row_ptr, eal, (const float4*)bs,
        hA16, nullptr, N);

    // --- layer 2: g1 = h1@W2 (MFMA); fused agg -> h2 (fp16) ---
    k_gemm_mfma<<<512, 256, 0, stream>>>(hA16, Ws + (size_t)D * D, gB16, N, NT64);
    k_agg<false, false><<<N / 4, 256, 0, stream>>>(
        (const float4*)gB16, nullptr, row_ptr, eal, (const float4*)(bs + D),
        hA16, nullptr, N);

    // --- layer 3: g2 = h2@W3 (MFMA); fused agg -> out (fp32, nontemporal) ---
    k_gemm_mfma<<<512, 256, 0, stream>>>(hA16, Ws + (size_t)2 * D * D, gB16, N, NT64);
    k_agg<false, true><<<N / 4, 256, 0, stream>>>(
        (const float4*)gB16, nullptr, row_ptr, eal, (const float4*)(bs + 2 * D),
        nullptr, out, N);
}